// Round 1
// baseline (2565.083 us; speedup 1.0000x reference)
//
#include <hip/hip_runtime.h>
#include <math.h>

// Problem constants (from reference): KSIZE=3, STRIDE=1, RATE=2, FUSE_K=3, SCALE=10
#define CDIM 128
#define HF   128
#define WF   128
#define HD   64
#define WD   64
#define NP   4096   // HD*WD patches == downsampled positions

// ---------------------------------------------------------------------------
// K1: downsample f,b by 2 (f[:, :, ::2, ::2])
__global__ __launch_bounds__(256) void k_downsample(const float* __restrict__ f,
                                                    const float* __restrict__ b,
                                                    float* __restrict__ fds,
                                                    float* __restrict__ bds) {
  int idx = blockIdx.x * 256 + threadIdx.x;          // CDIM*HD*WD = 524288 threads
  int x = idx & 63, y = (idx >> 6) & 63, c = idx >> 12;
  int src = c * HF * WF + (y * 2) * WF + x * 2;
  fds[idx] = f[src];
  bds[idx] = b[src];
}

// K1b: mm[p] = (sum of 3x3 window of downsampled mask == 0) ? 1 : 0
__global__ __launch_bounds__(256) void k_mm(const float* __restrict__ mask,
                                            float* __restrict__ mmv) {
  int p = blockIdx.x * 256 + threadIdx.x;            // NP threads
  int xb = p & 63, yb = p >> 6;
  float s = 0.f;
  for (int dy = -1; dy <= 1; ++dy)
    for (int dx = -1; dx <= 1; ++dx) {
      int y = yb + dy, x = xb + dx;
      if ((unsigned)y < (unsigned)HD && (unsigned)x < (unsigned)WD)
        s += mask[(2 * y) * WF + 2 * x];
    }
  mmv[p] = (s == 0.0f) ? 1.0f : 0.0f;
}

// K2a: s2[p] = sum_c bds[c,p]^2
__global__ __launch_bounds__(256) void k_sumsq(const float* __restrict__ bds,
                                               float* __restrict__ s2) {
  int p = blockIdx.x * 256 + threadIdx.x;            // NP threads
  float s = 0.f;
  for (int c = 0; c < CDIM; ++c) { float v = bds[c * NP + p]; s += v * v; }
  s2[p] = s;
}

// K2b: nrm[p] = sqrt(sum 3x3 window of s2 + 1152*1e-4)
__global__ __launch_bounds__(256) void k_norm(const float* __restrict__ s2,
                                              float* __restrict__ nrm) {
  int p = blockIdx.x * 256 + threadIdx.x;
  int xb = p & 63, yb = p >> 6;
  float s = 0.f;
  for (int dy = -1; dy <= 1; ++dy)
    for (int dx = -1; dx <= 1; ++dx) {
      int y = yb + dy, x = xb + dx;
      if ((unsigned)y < (unsigned)HD && (unsigned)x < (unsigned)WD)
        s += s2[y * 64 + x];
    }
  nrm[p] = sqrtf(s + 1152.0f * 1.0e-4f);
}

// Generic fp32 tiled GEMM: Out[m,n] = sum_k A[k*lda + m] * B[k*ldb + n]
// (both operands reduction-major). 64x64 tile / block, 256 threads, 4x4 micro.
__global__ __launch_bounds__(256) void k_gemm(const float* __restrict__ A,
                                              const float* __restrict__ B,
                                              float* __restrict__ Out,
                                              int Kdim, int lda, int ldb, int ldo) {
  __shared__ float As[8][64];
  __shared__ float Bs[8][64];
  int tid = threadIdx.x;
  int tx = tid & 15, ty = tid >> 4;
  int m0 = blockIdx.y * 64, n0 = blockIdx.x * 64;
  float acc[4][4] = {};
  int lr = tid >> 5;            // 0..7
  int lc = (tid & 31) * 2;      // 0..62
  for (int k0 = 0; k0 < Kdim; k0 += 8) {
    As[lr][lc]     = A[(k0 + lr) * lda + m0 + lc];
    As[lr][lc + 1] = A[(k0 + lr) * lda + m0 + lc + 1];
    Bs[lr][lc]     = B[(k0 + lr) * ldb + n0 + lc];
    Bs[lr][lc + 1] = B[(k0 + lr) * ldb + n0 + lc + 1];
    __syncthreads();
#pragma unroll
    for (int cc = 0; cc < 8; ++cc) {
      float4 av = *reinterpret_cast<const float4*>(&As[cc][ty << 2]);
      float4 bv = *reinterpret_cast<const float4*>(&Bs[cc][tx << 2]);
      float a[4] = {av.x, av.y, av.z, av.w};
      float b4[4] = {bv.x, bv.y, bv.z, bv.w};
#pragma unroll
      for (int i = 0; i < 4; ++i)
#pragma unroll
        for (int j = 0; j < 4; ++j) acc[i][j] += a[i] * b4[j];
    }
    __syncthreads();
  }
#pragma unroll
  for (int i = 0; i < 4; ++i)
#pragma unroll
    for (int j = 0; j < 4; ++j)
      Out[(size_t)(m0 + (ty << 2) + i) * ldo + n0 + (tx << 2) + j] = acc[i][j];
}

// K4a: S0[p,q] = (sum of 9 diagonal-2D-shifted D taps) / nrm[p]
__global__ __launch_bounds__(256) void k_s0(const float* __restrict__ D,
                                            const float* __restrict__ nrm,
                                            float* __restrict__ S0) {
  int idx = blockIdx.x * 256 + threadIdx.x;          // NP*NP threads (16.7M)
  int q = idx & 4095, p = idx >> 12;
  int yb = p >> 6, xb = p & 63, qy = q >> 6, qx = q & 63;
  float s = 0.f;
#pragma unroll
  for (int dy = -1; dy <= 1; ++dy)
#pragma unroll
    for (int dx = -1; dx <= 1; ++dx) {
      int yb2 = yb + dy, xb2 = xb + dx, qy2 = qy + dy, qx2 = qx + dx;
      if ((unsigned)yb2 < 64u && (unsigned)xb2 < 64u &&
          (unsigned)qy2 < 64u && (unsigned)qx2 < 64u)
        s += D[((yb2 * 64 + xb2) << 12) + (qy2 * 64 + qx2)];
    }
  S0[idx] = s / nrm[p];
}

// K4b: two fuse convs (identity-diagonal 3x3 on flattened 4096x4096, H-major
// then W-major flattening), times mm[u].
__global__ __launch_bounds__(256) void k_fuse(const float* __restrict__ S0,
                                              const float* __restrict__ mmv,
                                              float* __restrict__ L) {
  int idx = blockIdx.x * 256 + threadIdx.x;
  int v = idx & 4095, u = idx >> 12;
  float s = 0.f;
#pragma unroll
  for (int d2 = -1; d2 <= 1; ++d2) {
    int uw = ((u & 63) << 6) + (u >> 6) + d2;   // W-major flat index + d2
    int vw = ((v & 63) << 6) + (v >> 6) + d2;
    if ((unsigned)uw >= 4096u || (unsigned)vw >= 4096u) continue;
    int u2 = ((uw & 63) << 6) | (uw >> 6);      // back to H-major
    int v2 = ((vw & 63) << 6) | (vw >> 6);
#pragma unroll
    for (int d1 = -1; d1 <= 1; ++d1) {
      int u3 = u2 + d1, v3 = v2 + d1;
      if ((unsigned)u3 < 4096u && (unsigned)v3 < 4096u)
        s += S0[(u3 << 12) + v3];
    }
  }
  L[idx] = s * mmv[u];
}

// K5a: per-(column, u-chunk) online softmax partials of 10*L
__global__ __launch_bounds__(256) void k_smax_part(const float* __restrict__ L,
                                                   float* __restrict__ pm,
                                                   float* __restrict__ ps) {
  int v = blockIdx.x * 256 + threadIdx.x;      // 16 blocks in x
  int chunk = blockIdx.y;                      // 32 chunks of 128 rows
  float m = -1e30f, s = 0.f;
  int u0 = chunk * 128;
  for (int u = u0; u < u0 + 128; ++u) {
    float x = 10.0f * L[(u << 12) + v];
    if (x > m) { s = s * __expf(m - x) + 1.0f; m = x; }
    else       { s += __expf(x - m); }
  }
  pm[chunk * NP + v] = m;
  ps[chunk * NP + v] = s;
}

// K5a2: reduce 32 partials per column
__global__ __launch_bounds__(256) void k_smax_red(const float* __restrict__ pm,
                                                  const float* __restrict__ ps,
                                                  float* __restrict__ mcol,
                                                  float* __restrict__ scol) {
  int v = blockIdx.x * 256 + threadIdx.x;
  float m = -1e30f, s = 0.f;
  for (int ch = 0; ch < 32; ++ch) {
    float m2 = pm[ch * NP + v], s2 = ps[ch * NP + v];
    if (m2 > m) { s = s * __expf(m - m2) + s2; m = m2; }
    else        { s += s2 * __expf(m2 - m); }
  }
  mcol[v] = m;
  scol[v] = s;
}

// K5b: attn[u,v] = mm[u] * exp(10*L - mcol[v]) / scol[v]   (in place on L)
__global__ __launch_bounds__(256) void k_attn(float* __restrict__ L,
                                              const float* __restrict__ mcol,
                                              const float* __restrict__ scol,
                                              const float* __restrict__ mmv) {
  int idx = blockIdx.x * 256 + threadIdx.x;
  int v = idx & 4095, u = idx >> 12;
  float x = 10.0f * L[idx];
  L[idx] = mmv[u] * __expf(x - mcol[v]) / scol[v];
}

// K6pre: Vtp[p, k] with k = c*16 + dy*4 + dx; raw 4x4 patches of full-res b
__global__ __launch_bounds__(256) void k_vt(const float* __restrict__ b,
                                            float* __restrict__ Vtp) {
  int idx = blockIdx.x * 256 + threadIdx.x;    // NP*2048 threads
  int k = idx & 2047, p = idx >> 11;
  int dx = k & 3, dy = (k >> 2) & 3, c = k >> 4;
  int yb = p >> 6, xb = p & 63;
  int sy = 2 * yb + dy - 1, sx = 2 * xb + dx - 1;
  float v = 0.f;
  if ((unsigned)sy < (unsigned)HF && (unsigned)sx < (unsigned)WF)
    v = b[c * HF * WF + sy * WF + sx];
  Vtp[idx] = v;
}

// K7: scatter M[(c,dy,dx), q] into output (transposed conv, lhs_dilation=2), /4
__global__ __launch_bounds__(256) void k_scatter(const float* __restrict__ M,
                                                 float* __restrict__ out) {
  int idx = blockIdx.x * 256 + threadIdx.x;    // CDIM*HF*WF threads
  int ox = idx & 127, oy = (idx >> 7) & 127, c = idx >> 14;
  int qy[2], dyv[2], qx[2], dxv[2];
  if (oy & 1) { qy[0] = (oy - 1) >> 1; dyv[0] = 2; qy[1] = (oy + 1) >> 1; dyv[1] = 0; }
  else        { qy[0] = (oy >> 1) - 1; dyv[0] = 3; qy[1] = oy >> 1;       dyv[1] = 1; }
  if (ox & 1) { qx[0] = (ox - 1) >> 1; dxv[0] = 2; qx[1] = (ox + 1) >> 1; dxv[1] = 0; }
  else        { qx[0] = (ox >> 1) - 1; dxv[0] = 3; qx[1] = ox >> 1;       dxv[1] = 1; }
  float s = 0.f;
#pragma unroll
  for (int i = 0; i < 2; ++i) {
    if ((unsigned)qy[i] >= 64u) continue;
#pragma unroll
    for (int j = 0; j < 2; ++j) {
      if ((unsigned)qx[j] >= 64u) continue;
      int k = c * 16 + dyv[i] * 4 + dxv[j];
      s += M[(size_t)k * NP + qy[i] * 64 + qx[j]];
    }
  }
  out[idx] = 0.25f * s;
}

// ---------------------------------------------------------------------------
extern "C" void kernel_launch(void* const* d_in, const int* in_sizes, int n_in,
                              void* d_out, int out_size, void* d_ws, size_t ws_size,
                              hipStream_t stream) {
  const float* f_all = (const float*)d_in[0];   // (2,128,128,128)
  const float* b_all = (const float*)d_in[1];   // (2,128,128,128)
  const float* m_all = (const float*)d_in[2];   // (2,1,128,128)
  float* out = (float*)d_out;                   // (2,128,128,128)

  float* ws = (float*)d_ws;
  float* bufD = ws;                       // 16777216 floats: D, then L, then attn
  float* bufS = ws + 16777216;            // 16777216 floats: S0, then {Vtp, M}
  float* fds  = ws + 2 * 16777216;        // 524288
  float* bds  = fds + 524288;             // 524288
  float* s2   = bds + 524288;             // 4096
  float* nrm  = s2 + 4096;                // 4096
  float* mmv  = nrm + 4096;               // 4096
  float* pm   = mmv + 4096;               // 131072
  float* ps   = pm + 131072;              // 131072
  float* mcol = ps + 131072;              // 4096
  float* scol = mcol + 4096;              // 4096
  float* Vtp  = bufS;                     // 8388608 (reuses S0 space)
  float* Mbuf = bufS + 8388608;           // 8388608

  for (int it = 0; it < 2; ++it) {
    const float* f = f_all + (size_t)it * CDIM * HF * WF;
    const float* b = b_all + (size_t)it * CDIM * HF * WF;
    const float* mk = m_all + (size_t)it * HF * WF;
    float* o = out + (size_t)it * CDIM * HF * WF;

    k_downsample<<<2048, 256, 0, stream>>>(f, b, fds, bds);
    k_mm<<<16, 256, 0, stream>>>(mk, mmv);
    k_sumsq<<<16, 256, 0, stream>>>(bds, s2);
    k_norm<<<16, 256, 0, stream>>>(s2, nrm);
    // D = bds^T @ fds : Out[p,q], K=128
    k_gemm<<<dim3(64, 64), 256, 0, stream>>>(bds, fds, bufD, CDIM, NP, NP, NP);
    k_s0<<<65536, 256, 0, stream>>>(bufD, nrm, bufS);
    k_fuse<<<65536, 256, 0, stream>>>(bufS, mmv, bufD);
    k_smax_part<<<dim3(16, 32), 256, 0, stream>>>(bufD, pm, ps);
    k_smax_red<<<16, 256, 0, stream>>>(pm, ps, mcol, scol);
    k_attn<<<65536, 256, 0, stream>>>(bufD, mcol, scol, mmv);
    k_vt<<<32768, 256, 0, stream>>>(b, Vtp);
    // M = Vtp^T @ attn : Out[k,q], K=NP
    k_gemm<<<dim3(64, 32), 256, 0, stream>>>(Vtp, bufD, Mbuf, NP, 2048, NP, NP);
    k_scatter<<<8192, 256, 0, stream>>>(Mbuf, o);
  }
}

// Round 2
// 913.323 us; speedup vs baseline: 2.8085x; 2.8085x over previous
//
#include <hip/hip_runtime.h>
#include <math.h>

// KSIZE=3, STRIDE=1, RATE=2, FUSE_K=3, SCALE=10
#define CDIM 128
#define HF   128
#define WF   128
#define NP   4096   // 64*64 downsampled positions

typedef __attribute__((ext_vector_type(8))) short short8;
typedef __attribute__((ext_vector_type(4))) float floatx4;

__device__ inline ushort f2bf(float x) {
  union { float f; unsigned u; } v; v.f = x;
  unsigned r = v.u + 0x7fff + ((v.u >> 16) & 1);
  return (ushort)(r >> 16);
}
__device__ inline float bf2f(ushort h) {
  union { unsigned u; float f; } v; v.u = ((unsigned)h) << 16; return v.f;
}

// ---------------------------------------------------------------------------
// K1: downsample + split fp32 -> (hi,lo) bf16, write K-major concatenated
// operands for the split-precision score GEMM:
//   bcat[pos][0:128]=b_hi [128:256]=b_hi [256:384]=b_lo
//   fcat[pos][0:128]=f_hi [128:256]=f_lo [256:384]=f_hi
// so  bcat·fcat^T = bh·fh + bh·fl + bl·fh  ~= fp32 product.
__global__ __launch_bounds__(256) void k_prep(const float* __restrict__ f,
                                              const float* __restrict__ b,
                                              ushort* __restrict__ fcat,
                                              ushort* __restrict__ bcat) {
  int idx = blockIdx.x * 256 + threadIdx.x;   // 524288
  int c = idx & 127, pos = idx >> 7;
  int x = pos & 63, y = pos >> 6;
  int src = c * 16384 + y * 256 + x * 2;
  float fv = f[src], bv = b[src];
  ushort fh = f2bf(fv); ushort fl = f2bf(fv - bf2f(fh));
  ushort bh = f2bf(bv); ushort bl = f2bf(bv - bf2f(bh));
  size_t base = (size_t)pos * 384;
  fcat[base + c] = fh; fcat[base + 128 + c] = fl; fcat[base + 256 + c] = fh;
  bcat[base + c] = bh; bcat[base + 128 + c] = bh; bcat[base + 256 + c] = bl;
}

// mm[p] = (3x3 window sum of downsampled mask == 0) ? 1 : 0
__global__ __launch_bounds__(256) void k_mm(const float* __restrict__ mask,
                                            float* __restrict__ mmv) {
  int p = blockIdx.x * 256 + threadIdx.x;
  int xb = p & 63, yb = p >> 6;
  float s = 0.f;
  for (int dy = -1; dy <= 1; ++dy)
    for (int dx = -1; dx <= 1; ++dx) {
      int y = yb + dy, x = xb + dx;
      if ((unsigned)y < 64u && (unsigned)x < 64u)
        s += mask[y * 256 + x * 2];
    }
  mmv[p] = (s == 0.0f) ? 1.0f : 0.0f;
}

// s2[p] = sum_c b_ds[c,p]^2  (read full-res b directly, fp32 exact)
__global__ __launch_bounds__(256) void k_sumsq(const float* __restrict__ b,
                                               float* __restrict__ s2) {
  int p = blockIdx.x * 256 + threadIdx.x;
  int x = p & 63, y = p >> 6;
  float s = 0.f;
  for (int c = 0; c < CDIM; ++c) {
    float v = b[c * 16384 + y * 256 + x * 2];
    s += v * v;
  }
  s2[p] = s;
}

// nrm[p] = sqrt(3x3 window sum of s2 + 1152e-4)
__global__ __launch_bounds__(256) void k_norm(const float* __restrict__ s2,
                                              float* __restrict__ nrm) {
  int p = blockIdx.x * 256 + threadIdx.x;
  int xb = p & 63, yb = p >> 6;
  float s = 0.f;
  for (int dy = -1; dy <= 1; ++dy)
    for (int dx = -1; dx <= 1; ++dx) {
      int y = yb + dy, x = xb + dx;
      if ((unsigned)y < 64u && (unsigned)x < 64u) s += s2[y * 64 + x];
    }
  nrm[p] = sqrtf(s + 1152.0f * 1.0e-4f);
}

// ---------------------------------------------------------------------------
// MFMA bf16 GEMM: Out[m,n] = sum_k A[m*lda+k] * B[n*ldb+k]   (both K-major)
// 128x128 tile / block, 4 waves (2x2), BK=64, XOR-swizzled LDS (16B groups).
__global__ __launch_bounds__(256) void k_mfma_gemm(const ushort* __restrict__ A,
                                                   const ushort* __restrict__ B,
                                                   float* __restrict__ Out,
                                                   int Kdim, int lda, int ldb, int ldo) {
  __shared__ ushort As[128 * 64];
  __shared__ ushort Bs[128 * 64];
  int tid = threadIdx.x;
  int wave = tid >> 6, lane = tid & 63;
  int quad = lane >> 4, l16 = lane & 15;
  int m0 = blockIdx.y * 128, n0 = blockIdx.x * 128;
  int wm = (wave >> 1) * 64, wn = (wave & 1) * 64;

  floatx4 acc[4][4];
#pragma unroll
  for (int i = 0; i < 4; ++i)
#pragma unroll
    for (int j = 0; j < 4; ++j) acc[i][j] = (floatx4){0.f, 0.f, 0.f, 0.f};

  for (int k0 = 0; k0 < Kdim; k0 += 64) {
    // stage: 128 rows x 8 groups (16B) each for A and B; 4 groups/thread
#pragma unroll
    for (int p = 0; p < 4; ++p) {
      int gid = p * 256 + tid;            // 0..1023
      int m = gid >> 3, g = gid & 7;
      float4 av = *reinterpret_cast<const float4*>(A + (size_t)(m0 + m) * lda + k0 + g * 8);
      float4 bv = *reinterpret_cast<const float4*>(B + (size_t)(n0 + m) * ldb + k0 + g * 8);
      int gs = g ^ (m & 7);
      *reinterpret_cast<float4*>(&As[m * 64 + gs * 8]) = av;
      *reinterpret_cast<float4*>(&Bs[m * 64 + gs * 8]) = bv;
    }
    __syncthreads();
#pragma unroll
    for (int s = 0; s < 2; ++s) {
      short8 afrag[4], bfrag[4];
#pragma unroll
      for (int t = 0; t < 4; ++t) {
        int am = wm + t * 16 + l16;
        int ga = (s * 4 + quad) ^ (am & 7);
        afrag[t] = *reinterpret_cast<const short8*>(&As[am * 64 + ga * 8]);
        int bn = wn + t * 16 + l16;
        int gb = (s * 4 + quad) ^ (bn & 7);
        bfrag[t] = *reinterpret_cast<const short8*>(&Bs[bn * 64 + gb * 8]);
      }
#pragma unroll
      for (int i = 0; i < 4; ++i)
#pragma unroll
        for (int j = 0; j < 4; ++j)
          acc[i][j] = __builtin_amdgcn_mfma_f32_16x16x32_bf16(afrag[i], bfrag[j], acc[i][j], 0, 0, 0);
    }
    __syncthreads();
  }
  // C/D layout: col = lane&15, row = quad*4 + reg
#pragma unroll
  for (int i = 0; i < 4; ++i)
#pragma unroll
    for (int j = 0; j < 4; ++j)
#pragma unroll
      for (int r = 0; r < 4; ++r)
        Out[(size_t)(m0 + wm + i * 16 + quad * 4 + r) * ldo + (n0 + wn + j * 16 + l16)] = acc[i][j][r];
}

// ---------------------------------------------------------------------------
// S0[p,q] = (sum of 9 diagonally-2D-shifted D taps) / nrm[p]
__global__ __launch_bounds__(256) void k_s0(const float* __restrict__ D,
                                            const float* __restrict__ nrm,
                                            float* __restrict__ S0) {
  int idx = blockIdx.x * 256 + threadIdx.x;
  int q = idx & 4095, p = idx >> 12;
  int yb = p >> 6, xb = p & 63, qy = q >> 6, qx = q & 63;
  float s = 0.f;
#pragma unroll
  for (int dy = -1; dy <= 1; ++dy)
#pragma unroll
    for (int dx = -1; dx <= 1; ++dx) {
      int yb2 = yb + dy, xb2 = xb + dx, qy2 = qy + dy, qx2 = qx + dx;
      if ((unsigned)yb2 < 64u && (unsigned)xb2 < 64u &&
          (unsigned)qy2 < 64u && (unsigned)qx2 < 64u)
        s += D[((yb2 * 64 + xb2) << 12) + (qy2 * 64 + qx2)];
    }
  S0[idx] = s / nrm[p];
}

// two fuse convs (identity-diagonal 3x3 on flat 4096x4096, H-major then
// W-major flattening), times mm[u]
__global__ __launch_bounds__(256) void k_fuse(const float* __restrict__ S0,
                                              const float* __restrict__ mmv,
                                              float* __restrict__ L) {
  int idx = blockIdx.x * 256 + threadIdx.x;
  int v = idx & 4095, u = idx >> 12;
  float s = 0.f;
#pragma unroll
  for (int d2 = -1; d2 <= 1; ++d2) {
    int uw = ((u & 63) << 6) + (u >> 6) + d2;
    int vw = ((v & 63) << 6) + (v >> 6) + d2;
    if ((unsigned)uw >= 4096u || (unsigned)vw >= 4096u) continue;
    int u2 = ((uw & 63) << 6) | (uw >> 6);
    int v2 = ((vw & 63) << 6) | (vw >> 6);
#pragma unroll
    for (int d1 = -1; d1 <= 1; ++d1) {
      int u3 = u2 + d1, v3 = v2 + d1;
      if ((unsigned)u3 < 4096u && (unsigned)v3 < 4096u)
        s += S0[(u3 << 12) + v3];
    }
  }
  L[idx] = s * mmv[u];
}

// per-(column, chunk) online softmax partials of 10*L
__global__ __launch_bounds__(256) void k_smax_part(const float* __restrict__ L,
                                                   float* __restrict__ pm,
                                                   float* __restrict__ ps) {
  int v = blockIdx.x * 256 + threadIdx.x;
  int chunk = blockIdx.y;
  float m = -1e30f, s = 0.f;
  int u0 = chunk * 128;
  for (int u = u0; u < u0 + 128; ++u) {
    float x = 10.0f * L[((size_t)u << 12) + v];
    if (x > m) { s = s * __expf(m - x) + 1.0f; m = x; }
    else       { s += __expf(x - m); }
  }
  pm[chunk * NP + v] = m;
  ps[chunk * NP + v] = s;
}

__global__ __launch_bounds__(256) void k_smax_red(const float* __restrict__ pm,
                                                  const float* __restrict__ ps,
                                                  float* __restrict__ mcol,
                                                  float* __restrict__ scol) {
  int v = blockIdx.x * 256 + threadIdx.x;
  float m = -1e30f, s = 0.f;
  for (int ch = 0; ch < 32; ++ch) {
    float m2 = pm[ch * NP + v], s2 = ps[ch * NP + v];
    if (m2 > m) { s = s * __expf(m - m2) + s2; m = m2; }
    else        { s += s2 * __expf(m2 - m); }
  }
  mcol[v] = m;
  scol[v] = s;
}

// attnT[v,u] = bf16( mm[u] * exp(10*L[u,v] - mcol[v]) / scol[v] )
// 64x64 LDS tile transpose: coalesced read of L, coalesced write of attnT.
__global__ __launch_bounds__(256) void k_attnT(const float* __restrict__ L,
                                               const float* __restrict__ mcol,
                                               const float* __restrict__ scol,
                                               const float* __restrict__ mmv,
                                               ushort* __restrict__ AT) {
  __shared__ float T[64][65];
  int u0 = blockIdx.x * 64, v0 = blockIdx.y * 64;
  int tid = threadIdx.x;
  int i = tid >> 6, j = tid & 63;
#pragma unroll
  for (int r = 0; r < 16; ++r) {
    int u = u0 + r * 4 + i;
    float x = 10.0f * L[((size_t)u << 12) + v0 + j];
    T[r * 4 + i][j] = mmv[u] * __expf(x - mcol[v0 + j]) / scol[v0 + j];
  }
  __syncthreads();
#pragma unroll
  for (int r = 0; r < 16; ++r) {
    int v = v0 + r * 4 + i;
    AT[((size_t)v << 12) + u0 + j] = f2bf(T[j][r * 4 + i]);
  }
}

// VtT[k2][p] bf16, k2 = c*16 + dy*4 + dx: raw 4x4 patches of full-res b
__global__ __launch_bounds__(256) void k_vtT(const float* __restrict__ b,
                                             ushort* __restrict__ VtT) {
  int idx = blockIdx.x * 256 + threadIdx.x;   // 2048*4096
  int p = idx & 4095, k2 = idx >> 12;
  int dx = k2 & 3, dy = (k2 >> 2) & 3, c = k2 >> 4;
  int sy = 2 * (p >> 6) + dy - 1, sx = 2 * (p & 63) + dx - 1;
  float v = 0.f;
  if ((unsigned)sy < (unsigned)HF && (unsigned)sx < (unsigned)WF)
    v = b[c * 16384 + sy * 128 + sx];
  VtT[idx] = f2bf(v);
}

// scatter M[(c,dy,dx), q] -> out (transposed conv, lhs_dilation=2), /4
__global__ __launch_bounds__(256) void k_scatter(const float* __restrict__ M,
                                                 float* __restrict__ out) {
  int idx = blockIdx.x * 256 + threadIdx.x;
  int ox = idx & 127, oy = (idx >> 7) & 127, c = idx >> 14;
  int qy[2], dyv[2], qx[2], dxv[2];
  if (oy & 1) { qy[0] = (oy - 1) >> 1; dyv[0] = 2; qy[1] = (oy + 1) >> 1; dyv[1] = 0; }
  else        { qy[0] = (oy >> 1) - 1; dyv[0] = 3; qy[1] = oy >> 1;       dyv[1] = 1; }
  if (ox & 1) { qx[0] = (ox - 1) >> 1; dxv[0] = 2; qx[1] = (ox + 1) >> 1; dxv[1] = 0; }
  else        { qx[0] = (ox >> 1) - 1; dxv[0] = 3; qx[1] = ox >> 1;       dxv[1] = 1; }
  float s = 0.f;
#pragma unroll
  for (int i = 0; i < 2; ++i) {
    if ((unsigned)qy[i] >= 64u) continue;
#pragma unroll
    for (int j = 0; j < 2; ++j) {
      if ((unsigned)qx[j] >= 64u) continue;
      int k = c * 16 + dyv[i] * 4 + dxv[j];
      s += M[(size_t)k * NP + qy[i] * 64 + qx[j]];
    }
  }
  out[idx] = 0.25f * s;
}

// ---------------------------------------------------------------------------
extern "C" void kernel_launch(void* const* d_in, const int* in_sizes, int n_in,
                              void* d_out, int out_size, void* d_ws, size_t ws_size,
                              hipStream_t stream) {
  const float* f_all = (const float*)d_in[0];
  const float* b_all = (const float*)d_in[1];
  const float* m_all = (const float*)d_in[2];
  float* out = (float*)d_out;

  float* ws = (float*)d_ws;
  float* bufD = ws;                          // 16777216 floats: D -> L -> Mout
  float* bufS = ws + 16777216;               // 16777216 floats: {fcat,bcat} -> S0 -> {attnT, VtT}
  ushort* fcat = (ushort*)bufS;              // 4096*384 ushorts
  ushort* bcat = (ushort*)(bufS + 786432);   // 4096*384 ushorts
  ushort* attnT = (ushort*)bufS;             // 4096*4096 ushorts (32MB)
  ushort* VtT = (ushort*)(bufS + 8388608);   // 2048*4096 ushorts (16MB)
  float* smalls = ws + 2 * 16777216;
  float* s2   = smalls;                      // 4096
  float* nrm  = s2 + 4096;                   // 4096
  float* mmv  = nrm + 4096;                  // 4096
  float* pm   = mmv + 4096;                  // 131072
  float* ps   = pm + 131072;                 // 131072
  float* mcol = ps + 131072;                 // 4096
  float* scol = mcol + 4096;                 // 4096

  for (int it = 0; it < 2; ++it) {
    const float* f = f_all + (size_t)it * CDIM * HF * WF;
    const float* b = b_all + (size_t)it * CDIM * HF * WF;
    const float* mk = m_all + (size_t)it * HF * WF;
    float* o = out + (size_t)it * CDIM * HF * WF;

    k_prep<<<2048, 256, 0, stream>>>(f, b, fcat, bcat);
    k_mm<<<16, 256, 0, stream>>>(mk, mmv);
    k_sumsq<<<16, 256, 0, stream>>>(b, s2);
    k_norm<<<16, 256, 0, stream>>>(s2, nrm);
    // D[p,q] (fp32-accurate via split-bf16, K=384)
    k_mfma_gemm<<<dim3(32, 32), 256, 0, stream>>>(bcat, fcat, bufD, 384, 384, 384, NP);
    k_s0<<<65536, 256, 0, stream>>>(bufD, nrm, bufS);     // S0 clobbers fcat/bcat (dead)
    k_fuse<<<65536, 256, 0, stream>>>(bufS, mmv, bufD);   // L
    k_smax_part<<<dim3(16, 32), 256, 0, stream>>>(bufD, pm, ps);
    k_smax_red<<<16, 256, 0, stream>>>(pm, ps, mcol, scol);
    k_attnT<<<dim3(64, 64), 256, 0, stream>>>(bufD, mcol, scol, mmv, attnT);
    k_vtT<<<32768, 256, 0, stream>>>(b, VtT);
    // M[k2,q] = sum_p VtT[k2,p] * attnT[q,p]   (K=4096)
    k_mfma_gemm<<<dim3(32, 16), 256, 0, stream>>>(VtT, attnT, bufD, NP, NP, NP, NP);
    k_scatter<<<8192, 256, 0, stream>>>(bufD, o);
  }
}

// Round 3
// 888.533 us; speedup vs baseline: 2.8869x; 1.0279x over previous
//
#include <hip/hip_runtime.h>
#include <math.h>

// KSIZE=3, STRIDE=1, RATE=2, FUSE_K=3, SCALE=10
#define CDIM 128
#define HF   128
#define WF   128
#define NP   4096   // 64*64 downsampled positions

typedef __attribute__((ext_vector_type(8))) short short8;
typedef __attribute__((ext_vector_type(4))) float floatx4;

__device__ inline ushort f2bf(float x) {
  union { float f; unsigned u; } v; v.f = x;
  unsigned r = v.u + 0x7fff + ((v.u >> 16) & 1);
  return (ushort)(r >> 16);
}
__device__ inline float bf2f(ushort h) {
  union { unsigned u; float f; } v; v.u = ((unsigned)h) << 16; return v.f;
}

// async global->LDS, 16B per lane; LDS dest = base + lane*16 (wave-uniform base)
__device__ inline void gl2lds16(const ushort* g, ushort* l) {
  __builtin_amdgcn_global_load_lds((const __attribute__((address_space(1))) void*)g,
                                   (__attribute__((address_space(3))) void*)l, 16, 0, 0);
}

// ---------------------------------------------------------------------------
// K1: downsample + split fp32 -> (hi,lo) bf16, K-major concatenated operands:
//   bcat[pos][0:128]=b_hi [128:256]=b_hi [256:384]=b_lo
//   fcat[pos][0:128]=f_hi [128:256]=f_lo [256:384]=f_hi
// so bcat.fcat^T = bh.fh + bh.fl + bl.fh ~= fp32 product.
__global__ __launch_bounds__(256) void k_prep(const float* __restrict__ f,
                                              const float* __restrict__ b,
                                              ushort* __restrict__ fcat,
                                              ushort* __restrict__ bcat) {
  int idx = blockIdx.x * 256 + threadIdx.x;   // 524288
  int c = idx & 127, pos = idx >> 7;
  int x = pos & 63, y = pos >> 6;
  int src = c * 16384 + y * 256 + x * 2;
  float fv = f[src], bv = b[src];
  ushort fh = f2bf(fv); ushort fl = f2bf(fv - bf2f(fh));
  ushort bh = f2bf(bv); ushort bl = f2bf(bv - bf2f(bh));
  size_t base = (size_t)pos * 384;
  fcat[base + c] = fh; fcat[base + 128 + c] = fl; fcat[base + 256 + c] = fh;
  bcat[base + c] = bh; bcat[base + 128 + c] = bh; bcat[base + 256 + c] = bl;
}

// mmp[a] = mask-gate at p = pi(a)  (pi = 64x64 transpose involution)
__global__ __launch_bounds__(256) void k_mmp(const float* __restrict__ mask,
                                             float* __restrict__ mmp) {
  int a = blockIdx.x * 256 + threadIdx.x;
  int yb = a & 63, xb = a >> 6;               // p = pi(a) -> (yb, xb)
  float s = 0.f;
  for (int dy = -1; dy <= 1; ++dy)
    for (int dx = -1; dx <= 1; ++dx) {
      int y = yb + dy, x = xb + dx;
      if ((unsigned)y < 64u && (unsigned)x < 64u)
        s += mask[y * 256 + x * 2];
    }
  mmp[a] = (s == 0.0f) ? 1.0f : 0.0f;
}

// s2[p] = sum_c b_ds[c,p]^2 (fp32 exact, read full-res b)
__global__ __launch_bounds__(256) void k_sumsq(const float* __restrict__ b,
                                               float* __restrict__ s2) {
  int p = blockIdx.x * 256 + threadIdx.x;
  int x = p & 63, y = p >> 6;
  float s = 0.f;
  for (int c = 0; c < CDIM; ++c) {
    float v = b[c * 16384 + y * 256 + x * 2];
    s += v * v;
  }
  s2[p] = s;
}

// rnrm[p] = rsqrt(3x3 window sum of s2 + 1152e-4)
__global__ __launch_bounds__(256) void k_norm(const float* __restrict__ s2,
                                              float* __restrict__ rnrm) {
  int p = blockIdx.x * 256 + threadIdx.x;
  int xb = p & 63, yb = p >> 6;
  float s = 0.f;
  for (int dy = -1; dy <= 1; ++dy)
    for (int dx = -1; dx <= 1; ++dx) {
      int y = yb + dy, x = xb + dx;
      if ((unsigned)y < 64u && (unsigned)x < 64u) s += s2[y * 64 + x];
    }
  rnrm[p] = rsqrtf(s + 1152.0f * 1.0e-4f);
}

// ---------------------------------------------------------------------------
// MFMA bf16 GEMM, m97-style staging: Out[m,n] = sum_k A[m*lda+k]*B[n*ldb+k]
// 128x128 tile, 4 waves (2x2), BK=64, linear LDS [row][64] via global_load_lds.
__global__ __launch_bounds__(256) void k_mfma_gemm(const ushort* __restrict__ A,
                                                   const ushort* __restrict__ B,
                                                   float* __restrict__ Out,
                                                   int Kdim, int lda, int ldb, int ldo) {
  __shared__ ushort As[128 * 64];
  __shared__ ushort Bs[128 * 64];
  int tid = threadIdx.x;
  int wave = tid >> 6, lane = tid & 63;
  int quad = lane >> 4, l16 = lane & 15;
  int m0 = blockIdx.y * 128, n0 = blockIdx.x * 128;
  int wm = (wave >> 1) * 64, wn = (wave & 1) * 64;
  int srow = lane >> 3;          // 0..7: row within 8-row chunk
  int scol = (lane & 7) * 8;     // ushort col offset (16B granules)

  floatx4 acc[4][4];
#pragma unroll
  for (int i = 0; i < 4; ++i)
#pragma unroll
    for (int j = 0; j < 4; ++j) acc[i][j] = (floatx4){0.f, 0.f, 0.f, 0.f};

  for (int k0 = 0; k0 < Kdim; k0 += 64) {
#pragma unroll
    for (int i = 0; i < 4; ++i) {
      int rbase = wave * 32 + i * 8;       // wave-uniform
      gl2lds16(A + (size_t)(m0 + rbase + srow) * lda + k0 + scol, &As[rbase * 64]);
      gl2lds16(B + (size_t)(n0 + rbase + srow) * ldb + k0 + scol, &Bs[rbase * 64]);
    }
    __syncthreads();
#pragma unroll
    for (int s = 0; s < 2; ++s) {
      short8 afrag[4], bfrag[4];
#pragma unroll
      for (int t = 0; t < 4; ++t) {
        afrag[t] = *reinterpret_cast<const short8*>(&As[(wm + t * 16 + l16) * 64 + s * 32 + quad * 8]);
        bfrag[t] = *reinterpret_cast<const short8*>(&Bs[(wn + t * 16 + l16) * 64 + s * 32 + quad * 8]);
      }
#pragma unroll
      for (int i = 0; i < 4; ++i)
#pragma unroll
        for (int j = 0; j < 4; ++j)
          acc[i][j] = __builtin_amdgcn_mfma_f32_16x16x32_bf16(afrag[i], bfrag[j], acc[i][j], 0, 0, 0);
    }
    __syncthreads();
  }
  // C/D layout: col = lane&15, row = quad*4 + reg
#pragma unroll
  for (int i = 0; i < 4; ++i)
#pragma unroll
    for (int j = 0; j < 4; ++j)
#pragma unroll
      for (int r = 0; r < 4; ++r)
        Out[(size_t)(m0 + wm + i * 16 + quad * 4 + r) * ldo + (n0 + wn + j * 16 + l16)] = acc[i][j][r];
}

// ---------------------------------------------------------------------------
// S0[p,q] = (sum of 9 diagonally-2D-shifted D taps) * rnrm[p]
__global__ __launch_bounds__(256) void k_s0(const float* __restrict__ D,
                                            const float* __restrict__ rnrm,
                                            float* __restrict__ S0) {
  int idx = blockIdx.x * 256 + threadIdx.x;
  int q = idx & 4095, p = idx >> 12;
  int yb = p >> 6, xb = p & 63, qy = q >> 6, qx = q & 63;
  float s = 0.f;
#pragma unroll
  for (int dy = -1; dy <= 1; ++dy)
#pragma unroll
    for (int dx = -1; dx <= 1; ++dx) {
      int yb2 = yb + dy, xb2 = xb + dx, qy2 = qy + dy, qx2 = qx + dx;
      if ((unsigned)yb2 < 64u && (unsigned)xb2 < 64u &&
          (unsigned)qy2 < 64u && (unsigned)qx2 < 64u)
        s += D[((yb2 * 64 + xb2) << 12) + (qy2 * 64 + qx2)];
    }
  S0[idx] = s * rnrm[p];
}

// fuse1: F1[i,j] = sum_d S0[i+d, j+d] (flat diag 3-tap, OOB dropped),
// written PERMUTED: Yp[pi(i)][b] = F1[i][pi(b)]  (LDS row shuffle, padded)
__global__ __launch_bounds__(256) void k_fuse1(const float* __restrict__ S0,
                                               float* __restrict__ Yp) {
  __shared__ float row[4160];                // 4096 + 64 pad: pos(j) = j + (j>>6)
  int i = blockIdx.x;
  int t = threadIdx.x;
  const float* r0 = S0 + (size_t)(i - 1) * 4096;
  const float* r1 = S0 + (size_t)i * 4096;
  const float* r2 = S0 + (size_t)(i + 1) * 4096;
  bool up = (i > 0), dn = (i < 4095);
#pragma unroll
  for (int jj = 0; jj < 16; ++jj) {
    int j = jj * 256 + t;
    float s = r1[j];
    if (up && j > 0)    s += r0[j - 1];
    if (dn && j < 4095) s += r2[j + 1];
    row[j + (j >> 6)] = s;
  }
  __syncthreads();
  int a = ((i & 63) << 6) | (i >> 6);        // pi(i)
  float* orow = Yp + (size_t)a * 4096;
#pragma unroll
  for (int bb = 0; bb < 16; ++bb) {
    int b = bb * 256 + t;
    int j = ((b & 63) << 6) | (b >> 6);      // pi(b)
    orow[b] = row[j + (j >> 6)];
  }
}

// fuse2 (primed domain): Lp[a,b] = (sum_d Yp[a+d, b+d]) * mmp[a]
__global__ __launch_bounds__(256) void k_fuse2(const float* __restrict__ Yp,
                                               const float* __restrict__ mmp,
                                               float* __restrict__ Lp) {
  int idx = blockIdx.x * 256 + threadIdx.x;
  int b = idx & 4095, a = idx >> 12;
  float s = Yp[idx];
  if (a > 0 && b > 0)       s += Yp[idx - 4097];
  if (a < 4095 && b < 4095) s += Yp[idx + 4097];
  Lp[idx] = s * mmp[a];
}

// per-(column b, chunk) online softmax partials of 10*Lp
__global__ __launch_bounds__(256) void k_smax_part(const float* __restrict__ Lp,
                                                   float* __restrict__ pm,
                                                   float* __restrict__ ps) {
  int v = blockIdx.x * 256 + threadIdx.x;
  int chunk = blockIdx.y;
  float m = -1e30f, s = 0.f;
  int u0 = chunk * 128;
  for (int u = u0; u < u0 + 128; ++u) {
    float x = 10.0f * Lp[((size_t)u << 12) + v];
    if (x > m) { s = s * __expf(m - x) + 1.0f; m = x; }
    else       { s += __expf(x - m); }
  }
  pm[chunk * NP + v] = m;
  ps[chunk * NP + v] = s;
}

__global__ __launch_bounds__(256) void k_smax_red(const float* __restrict__ pm,
                                                  const float* __restrict__ ps,
                                                  float* __restrict__ mcol,
                                                  float* __restrict__ rscol) {
  int v = blockIdx.x * 256 + threadIdx.x;
  float m = -1e30f, s = 0.f;
  for (int ch = 0; ch < 32; ++ch) {
    float m2 = pm[ch * NP + v], s2 = ps[ch * NP + v];
    if (m2 > m) { s = s * __expf(m - m2) + s2; m = m2; }
    else        { s += s2 * __expf(m2 - m); }
  }
  mcol[v] = m;
  rscol[v] = 1.0f / s;
}

// attnT: AT[q=pi(b)][a] = bf16( mmp[a]*exp(10*Lp[a,b]-mcol[b])*rscol[b] )
// 64x64 LDS tile; reads coalesced, writes dense 128B row segments.
__global__ __launch_bounds__(256) void k_attnT(const float* __restrict__ Lp,
                                               const float* __restrict__ mcol,
                                               const float* __restrict__ rscol,
                                               const float* __restrict__ mmp,
                                               ushort* __restrict__ AT) {
  __shared__ float T[64][65];
  int a0 = blockIdx.x * 64, b0 = blockIdx.y * 64;
  int t = threadIdx.x;
  int i = t >> 6, j = t & 63;
#pragma unroll
  for (int r = 0; r < 16; ++r) {
    int al = r * 4 + i;
    int a = a0 + al, b = b0 + j;
    float x = 10.0f * Lp[((size_t)a << 12) + b];
    T[al][j] = mmp[a] * __expf(x - mcol[b]) * rscol[b];
  }
  __syncthreads();
  int by0 = b0 >> 6;
#pragma unroll
  for (int r = 0; r < 16; ++r) {
    int bl = r * 4 + i;
    int q = bl * 64 + by0;                   // pi(b0 + bl)
    AT[((size_t)q << 12) + a0 + j] = f2bf(T[j][bl]);
  }
}

// VtT'[k2][a] = bf16(Vt[k2][pi(a)]): LDS 64x64 transpose per k2
__global__ __launch_bounds__(256) void k_vtT(const float* __restrict__ b,
                                             ushort* __restrict__ VtT) {
  __shared__ float T[64][65];
  int k2 = blockIdx.x;                       // 0..2047
  int t = threadIdx.x;
  int c = k2 >> 4, dy = (k2 >> 2) & 3, dx = k2 & 3;
  int px = t & 63;
#pragma unroll
  for (int r = 0; r < 16; ++r) {
    int py = r * 4 + (t >> 6);
    int sy = 2 * py + dy - 1, sx = 2 * px + dx - 1;
    float v = 0.f;
    if ((unsigned)sy < (unsigned)HF && (unsigned)sx < (unsigned)WF)
      v = b[c * 16384 + sy * 128 + sx];
    T[py][px] = v;
  }
  __syncthreads();
  ushort* orow = VtT + (size_t)k2 * 4096;
#pragma unroll
  for (int r = 0; r < 16; ++r) {
    int a = r * 256 + t;
    orow[a] = f2bf(T[a & 63][a >> 6]);       // p = pi(a)
  }
}

// scatter M[(c,dy,dx), q] -> out (transposed conv, lhs_dilation=2), /4
__global__ __launch_bounds__(256) void k_scatter(const float* __restrict__ M,
                                                 float* __restrict__ out) {
  int idx = blockIdx.x * 256 + threadIdx.x;
  int ox = idx & 127, oy = (idx >> 7) & 127, c = idx >> 14;
  int qy[2], dyv[2], qx[2], dxv[2];
  if (oy & 1) { qy[0] = (oy - 1) >> 1; dyv[0] = 2; qy[1] = (oy + 1) >> 1; dyv[1] = 0; }
  else        { qy[0] = (oy >> 1) - 1; dyv[0] = 3; qy[1] = oy >> 1;       dyv[1] = 1; }
  if (ox & 1) { qx[0] = (ox - 1) >> 1; dxv[0] = 2; qx[1] = (ox + 1) >> 1; dxv[1] = 0; }
  else        { qx[0] = (ox >> 1) - 1; dxv[0] = 3; qx[1] = ox >> 1;       dxv[1] = 1; }
  float s = 0.f;
#pragma unroll
  for (int i = 0; i < 2; ++i) {
    if ((unsigned)qy[i] >= 64u) continue;
#pragma unroll
    for (int j = 0; j < 2; ++j) {
      if ((unsigned)qx[j] >= 64u) continue;
      int k = c * 16 + dyv[i] * 4 + dxv[j];
      s += M[(size_t)k * NP + qy[i] * 64 + qx[j]];
    }
  }
  out[idx] = 0.25f * s;
}

// ---------------------------------------------------------------------------
extern "C" void kernel_launch(void* const* d_in, const int* in_sizes, int n_in,
                              void* d_out, int out_size, void* d_ws, size_t ws_size,
                              hipStream_t stream) {
  const float* f_all = (const float*)d_in[0];
  const float* b_all = (const float*)d_in[1];
  const float* m_all = (const float*)d_in[2];
  float* out = (float*)d_out;

  float* ws = (float*)d_ws;
  float* bufD = ws;                          // 64MB: D -> Yp -> {AT, VtT}
  float* bufS = ws + 16777216;               // 64MB: {fcat,bcat} -> S0 -> Lp -> M
  ushort* fcat = (ushort*)bufS;              // 4096*384
  ushort* bcat = (ushort*)(bufS + 786432);   // 4096*384
  float* S0  = bufS;
  float* Yp  = bufD;
  float* Lp  = bufS;
  ushort* AT  = (ushort*)bufD;               // 4096*4096 bf16 (32MB)
  ushort* VtT = (ushort*)(bufD + 8388608);   // 2048*4096 bf16 (16MB)
  float* Mbuf = bufS;                        // 2048*4096 fp32 (32MB)
  float* smalls = ws + 2 * 16777216;
  float* s2   = smalls;                      // 4096
  float* rnrm = s2 + 4096;                   // 4096
  float* mmp  = rnrm + 4096;                 // 4096
  float* pm   = mmp + 4096;                  // 131072
  float* ps   = pm + 131072;                 // 131072
  float* mcol = ps + 131072;                 // 4096
  float* rscol = mcol + 4096;                // 4096

  for (int it = 0; it < 2; ++it) {
    const float* f = f_all + (size_t)it * CDIM * HF * WF;
    const float* b = b_all + (size_t)it * CDIM * HF * WF;
    const float* mk = m_all + (size_t)it * HF * WF;
    float* o = out + (size_t)it * CDIM * HF * WF;

    k_prep<<<2048, 256, 0, stream>>>(f, b, fcat, bcat);
    k_mmp<<<16, 256, 0, stream>>>(mk, mmp);
    k_sumsq<<<16, 256, 0, stream>>>(b, s2);
    k_norm<<<16, 256, 0, stream>>>(s2, rnrm);
    // D[p,q] (fp32-accurate via split-bf16, K=384)
    k_mfma_gemm<<<dim3(32, 32), 256, 0, stream>>>(bcat, fcat, bufD, 384, 384, 384, NP);
    k_s0<<<65536, 256, 0, stream>>>(bufD, rnrm, S0);      // S0 clobbers fcat/bcat (dead)
    k_fuse1<<<4096, 256, 0, stream>>>(S0, Yp);            // Yp clobbers D (dead)
    k_fuse2<<<65536, 256, 0, stream>>>(Yp, mmp, Lp);      // Lp clobbers S0 (dead)
    k_smax_part<<<dim3(16, 32), 256, 0, stream>>>(Lp, pm, ps);
    k_smax_red<<<16, 256, 0, stream>>>(pm, ps, mcol, rscol);
    k_attnT<<<dim3(64, 64), 256, 0, stream>>>(Lp, mcol, rscol, mmp, AT);  // AT clobbers Yp (dead)
    k_vtT<<<2048, 256, 0, stream>>>(b, VtT);
    // M[k2,q] = sum_a VtT[k2,a] * AT[q,a]   (K=4096)
    k_mfma_gemm<<<dim3(32, 16), 256, 0, stream>>>(VtT, AT, Mbuf, NP, NP, NP, NP);  // M clobbers Lp (dead)
    k_scatter<<<8192, 256, 0, stream>>>(Mbuf, o);
  }
}